// Round 7
// baseline (41.295 us; speedup 1.0000x reference)
//
#include <hip/hip_runtime.h>

#define NN 1024
#define HID 256
#define XD 128

// ws float offsets (all f32 now):
#define PX_OFF   0         // 1024*256, tiled: f32 idx = ((((jb*2+jj)*16+c)*4+q)*64+ln)*4+e
                           //   jb=j>>7, jj=(j>>6)&1, ln=j&63, c=k>>4, q=(k>>2)&3, e=k&3
#define PY_OFF   262144    // 1024*256 row-major [i][k], b1 folded in
#define W2_OFF   524288    // 256
#define C_OFF    524544    // 1024 : c[j] = exp(b2 - ls[j])
#define PART_OFF 525568    // 1024 : per-main-block exp-sum partials
#define T0P_OFF  526592    // 256  : per-prep-block T0 partials
#define LSP_OFF  526848    // 256  : per-prep-block ls partials

__global__ __launch_bounds__(512) void prep_kernel(
    const float* __restrict__ x, const float* __restrict__ y,
    const float* __restrict__ W1, const float* __restrict__ b1,
    const float* __restrict__ w2, const float* __restrict__ b2p,
    const float* __restrict__ wb, const float* __restrict__ bbp,
    float* __restrict__ wsF)
{
  __shared__ float sx[4][128];
  __shared__ float sy[4][128];
  __shared__ float spy2[4][256];
  __shared__ float st0[4][4];
  __shared__ float sls[4];
  const int t = threadIdx.x;
  const int blk = blockIdx.x;
  const int r0 = blk * 4;

  if (t < 128) {
    const int rl = t >> 5, f = t & 31;
    *(float4*)&sx[rl][f * 4] = *(const float4*)(x + (r0 + rl) * XD + f * 4);
  } else if (t < 256) {
    const int t2 = t - 128, rl = t2 >> 5, f = t2 & 31;
    *(float4*)&sy[rl][f * 4] = *(const float4*)(y + (r0 + rl) * XD + f * 4);
  }
  __syncthreads();

  const int side = t >> 8;   // waves 0-3: px side, waves 4-7: py side
  const int k = t & 255;
  float ap[4] = {0.f, 0.f, 0.f, 0.f};
  const float* wrow = W1 + k * 256 + side * 128;
  const float (*sm)[128] = side ? sy : sx;
#pragma unroll 8
  for (int dq = 0; dq < 32; ++dq) {
    float4 wv = *(const float4*)(wrow + dq * 4);
#pragma unroll
    for (int r = 0; r < 4; ++r) {
      float4 sv = *(const float4*)&sm[r][dq * 4];
      ap[r] = fmaf(sv.x, wv.x, ap[r]);
      ap[r] = fmaf(sv.y, wv.y, ap[r]);
      ap[r] = fmaf(sv.z, wv.z, ap[r]);
      ap[r] = fmaf(sv.w, wv.w, ap[r]);
    }
  }

  if (side == 1) {
    const float b1k = b1[k];
#pragma unroll
    for (int r = 0; r < 4; ++r) {
      ap[r] += b1k;
      spy2[r][k] = ap[r];
      wsF[PY_OFF + (r0 + r) * 256 + k] = ap[r];
    }
  } else {
    const int c = k >> 4, q = (k >> 2) & 3, e = k & 3;
#pragma unroll
    for (int r = 0; r < 4; ++r) {
      const int j = r0 + r;
      const int jb = j >> 7, jj = (j >> 6) & 1, ln = j & 63;
      wsF[PX_OFF + ((((jb * 2 + jj) * 16 + c) * 4 + q) * 64 + ln) * 4 + e] = ap[r];
    }
  }
  __syncthreads();

  if (side == 0) {
    const float w2k = w2[k];
    const int wv = t >> 6, lane = t & 63;
#pragma unroll
    for (int r = 0; r < 4; ++r) {
      float v = fmaxf(ap[r] + spy2[r][k], 0.f) * w2k;
      for (int o = 32; o > 0; o >>= 1) v += __shfl_down(v, o);
      if (lane == 0) st0[wv][r] = v;
    }
  } else if ((t & 255) < 128) {
    const int t2 = t & 255;
    const int rl = t2 >> 5, f = t2 & 31;
    float p = 0.f;
#pragma unroll
    for (int l = 0; l < 4; ++l) p = fmaf(sy[rl][f * 4 + l], wb[f * 4 + l], p);
    for (int m = 16; m > 0; m >>= 1) p += __shfl_xor(p, m);
    if (f == 0) {
      const float lsv = p + bbp[0];
      sls[rl] = lsv;
      wsF[C_OFF + r0 + rl] = __expf(b2p[0] - lsv);
    }
  }
  __syncthreads();

  if (t == 0) {
    const float b2v = b2p[0];
    float t0s = 0.f, lss = 0.f;
#pragma unroll
    for (int r = 0; r < 4; ++r) {
      t0s += st0[0][r] + st0[1][r] + st0[2][r] + st0[3][r] + b2v;
      lss += sls[r];
    }
    wsF[T0P_OFF + blk] = t0s;
    wsF[LSP_OFF + blk] = lss;
  }
  if (blk == 0 && t < 256) wsF[W2_OFF + t] = w2[t];
}

// grid 1024: bj = blk&7 (j-tile 128), i0 = (blk>>3)*8 (i-tile 8).  256 thr.
// Wave w handles k-chunks c = p*4+w (16 k each, 4 passes = 64 k).  px chunk
// in 32 VGPR (coalesced), w2 chunk 16 VGPR, py via LDS broadcast.  All f32
// scalar ops (verified full-rate).  Wave partials combined via sComb.
__global__ __launch_bounds__(256, 4) void main_kernel(
    const float* __restrict__ wsF, float* __restrict__ wsFo)
{
  __shared__ float spy[8 * 256];        // 8 KB
  __shared__ float sw2f[256];           // 1 KB
  __shared__ float sComb[4][8][128];    // 16 KB
  __shared__ float sred[4];
  const int t = threadIdx.x;
  const int lane = t & 63;
  const int w = t >> 6;                 // 0..3
  const int blk = blockIdx.x;
  const int bj = blk & 7;
  const int i0 = (blk >> 3) * 8;

  {
    const float4* gpy = (const float4*)(wsF + PY_OFF + (size_t)i0 * 256);
    ((float4*)spy)[t]       = gpy[t];
    ((float4*)spy)[t + 256] = gpy[t + 256];
    if (t < 64) ((float4*)sw2f)[t] = ((const float4*)(wsF + W2_OFF))[t];
  }
  __syncthreads();

  const float4* gpx = (const float4*)(wsF + PX_OFF);
  const float4* spy4 = (const float4*)spy;
  const float4* sw24 = (const float4*)sw2f;

  float acc[8][2];
#pragma unroll
  for (int ii = 0; ii < 8; ++ii) { acc[ii][0] = 0.f; acc[ii][1] = 0.f; }

#pragma unroll 1
  for (int p = 0; p < 4; ++p) {
    const int c = p * 4 + w;
    float4 pxr0[4], pxr1[4], wq[4];
#pragma unroll
    for (int q = 0; q < 4; ++q) {
      pxr0[q] = gpx[(((bj * 2 + 0) * 16 + c) * 4 + q) * 64 + lane];
      pxr1[q] = gpx[(((bj * 2 + 1) * 16 + c) * 4 + q) * 64 + lane];
      wq[q] = sw24[c * 4 + q];
    }
#pragma unroll
    for (int ii = 0; ii < 8; ++ii) {
#pragma unroll
      for (int q = 0; q < 4; ++q) {
        float4 pv = spy4[ii * 64 + c * 4 + q];
        float a0 = acc[ii][0], a1 = acc[ii][1];
        a0 = fmaf(fmaxf(pxr0[q].x + pv.x, 0.f), wq[q].x, a0);
        a1 = fmaf(fmaxf(pxr1[q].x + pv.x, 0.f), wq[q].x, a1);
        a0 = fmaf(fmaxf(pxr0[q].y + pv.y, 0.f), wq[q].y, a0);
        a1 = fmaf(fmaxf(pxr1[q].y + pv.y, 0.f), wq[q].y, a1);
        a0 = fmaf(fmaxf(pxr0[q].z + pv.z, 0.f), wq[q].z, a0);
        a1 = fmaf(fmaxf(pxr1[q].z + pv.z, 0.f), wq[q].z, a1);
        a0 = fmaf(fmaxf(pxr0[q].w + pv.w, 0.f), wq[q].w, a0);
        a1 = fmaf(fmaxf(pxr1[q].w + pv.w, 0.f), wq[q].w, a1);
        acc[ii][0] = a0; acc[ii][1] = a1;
      }
    }
  }

#pragma unroll
  for (int ii = 0; ii < 8; ++ii) {
    sComb[w][ii][lane]      = acc[ii][0];
    sComb[w][ii][64 + lane] = acc[ii][1];
  }
  __syncthreads();

  float ts = 0.f;
#pragma unroll
  for (int r = 0; r < 4; ++r) {
    const int pidx = t + r * 256;
    const int ii = pidx >> 7, jc = pidx & 127;
    float s = (sComb[0][ii][jc] + sComb[1][ii][jc])
            + (sComb[2][ii][jc] + sComb[3][ii][jc]);
    ts += __expf(s) * wsF[C_OFF + bj * 128 + jc];
  }
  for (int o = 32; o > 0; o >>= 1) ts += __shfl_down(ts, o);
  if (lane == 0) sred[w] = ts;
  __syncthreads();
  if (t == 0)
    wsFo[PART_OFF + blk] = (sred[0] + sred[1]) + (sred[2] + sred[3]);
}

__global__ __launch_bounds__(256) void fin_kernel(
    const float* __restrict__ wsF, float* __restrict__ out)
{
  __shared__ float sr[4][3];
  const int t = threadIdx.x;
  float4 ev = ((const float4*)(wsF + PART_OFF))[t];
  float e = (ev.x + ev.y) + (ev.z + ev.w);
  float t0 = wsF[T0P_OFF + t];
  float ls = wsF[LSP_OFF + t];
  for (int o = 32; o > 0; o >>= 1) {
    e  += __shfl_down(e, o);
    t0 += __shfl_down(t0, o);
    ls += __shfl_down(ls, o);
  }
  if ((t & 63) == 0) {
    sr[t >> 6][0] = e;
    sr[t >> 6][1] = t0;
    sr[t >> 6][2] = ls;
  }
  __syncthreads();
  if (t == 0) {
    const float es  = sr[0][0] + sr[1][0] + sr[2][0] + sr[3][0];
    const float t0s = sr[0][1] + sr[1][1] + sr[2][1] + sr[3][1];
    const float lss = sr[0][2] + sr[1][2] + sr[2][2] + sr[3][2];
    out[0] = 1.0f + t0s * (1.0f / 1024.0f) - lss * (1.0f / 1024.0f)
                  - es * (1.0f / 1048576.0f);
  }
}

extern "C" void kernel_launch(void* const* d_in, const int* in_sizes, int n_in,
                              void* d_out, int out_size, void* d_ws, size_t ws_size,
                              hipStream_t stream) {
  const float* x  = (const float*)d_in[0];
  const float* y  = (const float*)d_in[1];
  const float* W1 = (const float*)d_in[2];
  const float* b1 = (const float*)d_in[3];
  const float* w2 = (const float*)d_in[4];
  const float* b2 = (const float*)d_in[5];
  const float* wb = (const float*)d_in[6];
  const float* bb = (const float*)d_in[7];
  float* wsF = (float*)d_ws;
  float* out = (float*)d_out;

  hipLaunchKernelGGL(prep_kernel, dim3(256), dim3(512), 0, stream,
                     x, y, W1, b1, w2, b2, wb, bb, wsF);
  hipLaunchKernelGGL(main_kernel, dim3(1024), dim3(256), 0, stream, wsF, wsF);
  hipLaunchKernelGGL(fin_kernel, dim3(1), dim3(256), 0, stream, wsF, out);
}

// Round 8
// 39.691 us; speedup vs baseline: 1.0404x; 1.0404x over previous
//
#include <hip/hip_runtime.h>
#include <hip/hip_fp16.h>

#define NN 1024
#define HID 256
#define XD 128

typedef _Float16 h2 __attribute__((ext_vector_type(2)));
typedef _Float16 h8 __attribute__((ext_vector_type(8)));

// wsh (halves):
//   px [0, 262144)  tiled: idx = (((((jt*2+kh)*8+kg)*4+jj)*2+ks)*64+ln)*8 + kl
//       jt=j>>8, jj=(j>>6)&3, ln=j&63 ; kh=k>>7, kg=(k>>4)&7, ks=(k>>3)&1, kl=k&7
//   py [262144, 524288)  row-major [i][k]  (b1 folded in)
//   w2h [524288, 524544)
// wsf (floats) at byte 1049600:
#define WSF_BYTE_OFF 1049600
#define F_C     0        // 1024 : c[j] = exp(b2 - ls[j])
#define F_T0P   1024     // 256
#define F_LSP   1280     // 256
#define F_PART  1536     // 256 : per-combine-block partials
#define F_PA    4096     // 1048576 : kh=0 pre-exp partials [jt][ig][ii][jcol]
#define F_PB    1052672  // 1048576 : kh=1

__device__ __forceinline__ h2 relu2(h2 x) {
  h2 z = {(_Float16)0, (_Float16)0};
  return __builtin_elementwise_max(x, z);
}

__device__ __forceinline__ float dot2f(h2 a, h2 b, float c) {
  return __builtin_amdgcn_fdot2(a, b, c, false);
}

__global__ __launch_bounds__(256) void prep_kernel(
    const float* __restrict__ x, const float* __restrict__ y,
    const float* __restrict__ W1, const float* __restrict__ b1,
    const float* __restrict__ w2, const float* __restrict__ b2p,
    const float* __restrict__ wb, const float* __restrict__ bbp,
    _Float16* __restrict__ wsh, float* __restrict__ wsf)
{
  __shared__ float sx[4][128];
  __shared__ float sy[4][128];
  __shared__ float st0[4][4];
  __shared__ float sls[4];
  const int t = threadIdx.x;
  const int blk = blockIdx.x;
  const int r0 = blk * 4;

  {
    const int rl = (t & 127) >> 5, f = t & 31;
    if (t < 128) {
      *(float4*)&sx[rl][f * 4] = *(const float4*)(x + (r0 + rl) * XD + f * 4);
    } else {
      *(float4*)&sy[rl][f * 4] = *(const float4*)(y + (r0 + rl) * XD + f * 4);
    }
  }
  __syncthreads();

  const int k = t;  // one hidden unit per thread
  float apx[4] = {0,0,0,0};
  float apy[4] = {0,0,0,0};
  const float* wrow = W1 + k * 256;
  for (int dq = 0; dq < 32; ++dq) {
    float4 wx = *(const float4*)(wrow + dq * 4);
    float4 wy = *(const float4*)(wrow + 128 + dq * 4);
#pragma unroll
    for (int r = 0; r < 4; ++r) {
      float4 xv = *(const float4*)&sx[r][dq * 4];
      float4 yv = *(const float4*)&sy[r][dq * 4];
      apx[r] = fmaf(xv.x, wx.x, apx[r]);
      apx[r] = fmaf(xv.y, wx.y, apx[r]);
      apx[r] = fmaf(xv.z, wx.z, apx[r]);
      apx[r] = fmaf(xv.w, wx.w, apx[r]);
      apy[r] = fmaf(yv.x, wy.x, apy[r]);
      apy[r] = fmaf(yv.y, wy.y, apy[r]);
      apy[r] = fmaf(yv.z, wy.z, apy[r]);
      apy[r] = fmaf(yv.w, wy.w, apy[r]);
    }
  }
  const float b1k = b1[k];
#pragma unroll
  for (int r = 0; r < 4; ++r) apy[r] += b1k;  // fold b1 into py

  // px: tiled for main's coalesced per-(kh,kg) register loads; py row-major
  {
    _Float16* pxh = wsh;
    _Float16* pyh = wsh + 262144;
    const int kh = k >> 7, kg = (k >> 4) & 7, ks = (k >> 3) & 1, kl = k & 7;
#pragma unroll
    for (int r = 0; r < 4; ++r) {
      const int j = r0 + r;
      const int jt = j >> 8, jj = (j >> 6) & 3, ln = j & 63;
      pxh[(((((jt * 2 + kh) * 8 + kg) * 4 + jj) * 2 + ks) * 64 + ln) * 8 + kl]
          = (_Float16)apx[r];
      pyh[j * 256 + k] = (_Float16)apy[r];
    }
  }

  // T0 partials (exact f32)
  const float w2k = w2[k];
  const float b2v = b2p[0];
  const int wv = t >> 6, lane = t & 63;
#pragma unroll
  for (int r = 0; r < 4; ++r) {
    float v = fmaxf(apx[r] + apy[r], 0.f) * w2k;
    for (int o = 32; o > 0; o >>= 1) v += __shfl_down(v, o);
    if (lane == 0) st0[wv][r] = v;
  }

  // ls[r] = y[r].wb + bb ; c[r] = exp(b2 - ls[r])
  if (t < 128) {
    const int rl = t >> 5, f = t & 31;
    float p = 0.f;
#pragma unroll
    for (int l = 0; l < 4; ++l) p = fmaf(sy[rl][f * 4 + l], wb[f * 4 + l], p);
    for (int m = 16; m > 0; m >>= 1) p += __shfl_xor(p, m);
    if (f == 0) {
      const float lsv = p + bbp[0];
      sls[rl] = lsv;
      wsf[F_C + r0 + rl] = __expf(b2v - lsv);
    }
  }
  __syncthreads();
  if (t == 0) {
    float t0s = 0.f, lss = 0.f;
#pragma unroll
    for (int r = 0; r < 4; ++r) {
      t0s += st0[0][r] + st0[1][r] + st0[2][r] + st0[3][r] + b2v;
      lss += sls[r];
    }
    wsf[F_T0P + blk] = t0s;
    wsf[F_LSP + blk] = lss;
  }
  if (blk == 0 && t < 128) {
    h2 wv2;
    wv2.x = (_Float16)w2[2 * t];
    wv2.y = (_Float16)w2[2 * t + 1];
    ((h2*)(wsh + 524288))[t] = wv2;
  }
}

// grid 1024: blk -> kh = blk&1, ig = (blk>>1)&127, jt = blk>>8.
// Block tile: 256 j (4 per lane) x 8 i x 128 k (kh half).  8 waves; wave =
// kg (16 k).  px 32 VGPR (coalesced), w2 8 VGPR (hoisted), py via 16
// broadcast ds_read_b128 per thread (48:1 VALU:LDS).  kg partials combined
// by 3-round LDS tree; kg==0 waves store the pre-exp block tile to global.
__global__ __launch_bounds__(512, 4) void main_kernel(
    const _Float16* __restrict__ wsh, float* __restrict__ wsf)
{
  __shared__ _Float16 spy[8 * 128];    // 2 KB
  __shared__ _Float16 sw2[128];        // 256 B
  __shared__ float sComb[4][8][256];   // 32 KB
  const int t = threadIdx.x;
  const int lane = t & 63;
  const int kg = t >> 6;               // 0..7
  const int blk = blockIdx.x;
  const int kh = blk & 1;
  const int ig = (blk >> 1) & 127;
  const int jt = blk >> 8;

  // stage py rows [ig*8, +8), k-half kh (8 x 128 halves = 128 float4) + w2
  if (t < 128) {
    const int row = t >> 4, col = t & 15;
    ((float4*)spy)[t] =
        ((const float4*)(wsh + 262144))[(ig * 8 + row) * 32 + kh * 16 + col];
  } else if (t < 144) {
    ((float4*)sw2)[t - 128] = ((const float4*)(wsh + 524288))[kh * 16 + (t - 128)];
  }

  // px -> regs: 8 coalesced float4 (4 j x 16 k per lane)
  h8 pxA[4], pxB[4];
  {
    const float4* gpx = (const float4*)wsh;
    const int pbase = (((jt * 2 + kh) * 8 + kg) * 4) * 2 * 64 + lane;
#pragma unroll
    for (int jj = 0; jj < 4; ++jj) {
      *(float4*)&pxA[jj] = gpx[pbase + (jj * 2 + 0) * 64];
      *(float4*)&pxB[jj] = gpx[pbase + (jj * 2 + 1) * 64];
    }
  }
  __syncthreads();

  const h8* wf = (const h8*)(sw2 + kg * 16);
  h8 w0 = wf[0], w1 = wf[1];
  const h2* wA = (const h2*)&w0;
  const h2* wB = (const h2*)&w1;

  float acc[8][4];
#pragma unroll
  for (int ii = 0; ii < 8; ++ii)
#pragma unroll
    for (int jj = 0; jj < 4; ++jj) acc[ii][jj] = 0.f;

#pragma unroll
  for (int ii = 0; ii < 8; ++ii) {
    const h8* pf = (const h8*)(spy + ii * 128 + kg * 16);
    h8 p0 = pf[0], p1 = pf[1];          // 2 broadcast ds_read_b128
    const h2* pA = (const h2*)&p0;
    const h2* pB = (const h2*)&p1;
#pragma unroll
    for (int jj = 0; jj < 4; ++jj) {
      const h2* xA = (const h2*)&pxA[jj];
      const h2* xB = (const h2*)&pxB[jj];
      float s = acc[ii][jj];
      s = dot2f(relu2(xA[0] + pA[0]), wA[0], s);
      s = dot2f(relu2(xA[1] + pA[1]), wA[1], s);
      s = dot2f(relu2(xA[2] + pA[2]), wA[2], s);
      s = dot2f(relu2(xA[3] + pA[3]), wA[3], s);
      s = dot2f(relu2(xB[0] + pB[0]), wB[0], s);
      s = dot2f(relu2(xB[1] + pB[1]), wB[1], s);
      s = dot2f(relu2(xB[2] + pB[2]), wB[2], s);
      s = dot2f(relu2(xB[3] + pB[3]), wB[3], s);
      acc[ii][jj] = s;
    }
  }

  // 3-round tree combine over kg
  if (kg >= 4) {
#pragma unroll
    for (int ii = 0; ii < 8; ++ii)
#pragma unroll
      for (int jj = 0; jj < 4; ++jj)
        sComb[kg - 4][ii][jj * 64 + lane] = acc[ii][jj];
  }
  __syncthreads();
  if (kg < 4) {
#pragma unroll
    for (int ii = 0; ii < 8; ++ii)
#pragma unroll
      for (int jj = 0; jj < 4; ++jj)
        acc[ii][jj] += sComb[kg][ii][jj * 64 + lane];
  }
  __syncthreads();
  if (kg == 2 || kg == 3) {
#pragma unroll
    for (int ii = 0; ii < 8; ++ii)
#pragma unroll
      for (int jj = 0; jj < 4; ++jj)
        sComb[kg - 2][ii][jj * 64 + lane] = acc[ii][jj];
  }
  __syncthreads();
  if (kg < 2) {
#pragma unroll
    for (int ii = 0; ii < 8; ++ii)
#pragma unroll
      for (int jj = 0; jj < 4; ++jj)
        acc[ii][jj] += sComb[kg][ii][jj * 64 + lane];
  }
  __syncthreads();
  if (kg == 1) {
#pragma unroll
    for (int ii = 0; ii < 8; ++ii)
#pragma unroll
      for (int jj = 0; jj < 4; ++jj)
        sComb[0][ii][jj * 64 + lane] = acc[ii][jj];
  }
  __syncthreads();
  if (kg == 0) {
    float* pout = wsf + (kh ? F_PB : F_PA) + (size_t)((jt * 128 + ig) * 8) * 256;
#pragma unroll
    for (int ii = 0; ii < 8; ++ii)
#pragma unroll
      for (int jj = 0; jj < 4; ++jj)
        pout[ii * 256 + jj * 64 + lane] =
            acc[ii][jj] + sComb[0][ii][jj * 64 + lane];
  }
}

// grid 256 x 256 thr: sum the two kh halves, exp, * c_j, reduce.
__global__ __launch_bounds__(256) void combine_kernel(
    const float* __restrict__ wsf, float* __restrict__ wsfo)
{
  __shared__ float sred[4];
  const int t = threadIdx.x;
  const int blk = blockIdx.x;
  const float4* pA4 = (const float4*)(wsf + F_PA);
  const float4* pB4 = (const float4*)(wsf + F_PB);
  float ts = 0.f;
#pragma unroll
  for (int r = 0; r < 4; ++r) {
    const int idx4 = blk * 1024 + r * 256 + t;
    float4 a = pA4[idx4];
    float4 b = pB4[idx4];
    const int jt = idx4 >> 16;
    float4 c4 = ((const float4*)(wsf + F_C + jt * 256))[idx4 & 63];
    ts += __expf(a.x + b.x) * c4.x + __expf(a.y + b.y) * c4.y
        + __expf(a.z + b.z) * c4.z + __expf(a.w + b.w) * c4.w;
  }
  for (int o = 32; o > 0; o >>= 1) ts += __shfl_down(ts, o);
  if ((t & 63) == 0) sred[t >> 6] = ts;
  __syncthreads();
  if (t == 0)
    wsfo[F_PART + blk] = (sred[0] + sred[1]) + (sred[2] + sred[3]);
}

__global__ __launch_bounds__(256) void fin_kernel(
    const float* __restrict__ wsf, float* __restrict__ out)
{
  __shared__ float sr[4][3];
  const int t = threadIdx.x;
  float e  = wsf[F_PART + t];
  float t0 = wsf[F_T0P + t];
  float ls = wsf[F_LSP + t];
  for (int o = 32; o > 0; o >>= 1) {
    e  += __shfl_down(e, o);
    t0 += __shfl_down(t0, o);
    ls += __shfl_down(ls, o);
  }
  if ((t & 63) == 0) {
    sr[t >> 6][0] = e;
    sr[t >> 6][1] = t0;
    sr[t >> 6][2] = ls;
  }
  __syncthreads();
  if (t == 0) {
    const float es  = sr[0][0] + sr[1][0] + sr[2][0] + sr[3][0];
    const float t0s = sr[0][1] + sr[1][1] + sr[2][1] + sr[3][1];
    const float lss = sr[0][2] + sr[1][2] + sr[2][2] + sr[3][2];
    out[0] = 1.0f + t0s * (1.0f / 1024.0f) - lss * (1.0f / 1024.0f)
                  - es * (1.0f / 1048576.0f);
  }
}

extern "C" void kernel_launch(void* const* d_in, const int* in_sizes, int n_in,
                              void* d_out, int out_size, void* d_ws, size_t ws_size,
                              hipStream_t stream) {
  const float* x  = (const float*)d_in[0];
  const float* y  = (const float*)d_in[1];
  const float* W1 = (const float*)d_in[2];
  const float* b1 = (const float*)d_in[3];
  const float* w2 = (const float*)d_in[4];
  const float* b2 = (const float*)d_in[5];
  const float* wb = (const float*)d_in[6];
  const float* bb = (const float*)d_in[7];
  _Float16* wsh = (_Float16*)d_ws;
  float* wsf = (float*)((char*)d_ws + WSF_BYTE_OFF);
  float* out = (float*)d_out;

  hipLaunchKernelGGL(prep_kernel, dim3(256), dim3(256), 0, stream,
                     x, y, W1, b1, w2, b2, wb, bb, wsh, wsf);
  hipLaunchKernelGGL(main_kernel, dim3(1024), dim3(512), 0, stream, wsh, wsf);
  hipLaunchKernelGGL(combine_kernel, dim3(256), dim3(256), 0, stream, wsf, wsf);
  hipLaunchKernelGGL(fin_kernel, dim3(1), dim3(256), 0, stream, wsf, out);
}